// Round 5
// baseline (264.618 us; speedup 1.0000x reference)
//
#include <hip/hip_runtime.h>
#include <math.h>

#define TWO_PI_F 6.283185307179586f

typedef __fp16 half2_t __attribute__((ext_vector_type(2)));
typedef __fp16 half8_t __attribute__((ext_vector_type(8)));
typedef float  f32x4   __attribute__((ext_vector_type(4)));
typedef unsigned u32x2 __attribute__((ext_vector_type(2)));

// ---- d_ws layout (u32 units) ----
#define OFF_EW1   0       // [64][2]   enc_w1 f16 pairs over K
#define OFF_A     128     // [4][64][4] enc2 A-frags (mt*2+kt, lane, reg)
#define OFF_B2I   1152    // [2][64][4] enc2 bias in C-layout (mt, lane, reg) f32
#define OFF_ENCF  1664    // [3][16]   folded (ew3@pw) f16 pairs over K
#define OFF_ENCFB 1712    // [3] f32   folded bias
#define OFF_FWH   1716    // [10][32]  (wh[l][0][j], odd? wh[l][1][j]:0) pairs
#define OFF_FMU1E 2036    // [10][8]   even-k packed wmu[:,1]: (w[4p],w[4p+2])
#define OFF_FA1E  2116    // [10][8]   even-k packed wa[:,1]
#define OFF_FMU2  2196    // [10][16]  wmu[:,2] pairs
#define OFF_FA2   2356    // [10][16]  wa[:,2] pairs
#define OFF_C0    2516    // [10] f32  exp(-tanh(ba[l][0]))
// total 2526 u32

// LDS: per-wave slice, 64 rows x 72B (16 u32 data + 2 pad)
#define ROW_STRIDE 72
#define WAVE_SLICE (64 * ROW_STRIDE)   // 4608 B

__device__ __forceinline__ unsigned pack2(float a, float b) {
    half2_t h = __builtin_amdgcn_cvt_pkrtz(a, b);
    union { half2_t h; unsigned u; } cvt;
    cvt.h = h;
    return cvt.u;
}

__global__ __launch_bounds__(256)
void gsi_setup(const float* __restrict__ ew1, const float* __restrict__ ew2,
               const float* __restrict__ eb2,
               const float* __restrict__ ew3, const float* __restrict__ eb3,
               const float* __restrict__ pw,  const float* __restrict__ pb,
               const float* __restrict__ fwh, const float* __restrict__ fwmu,
               const float* __restrict__ fwa, const float* __restrict__ fba,
               unsigned* __restrict__ ws)
{
    int t = threadIdx.x;

    // enc_w1 (4,64): pairs over k
    for (int idx = t; idx < 128; idx += 256) {
        int j = idx >> 1, kk = idx & 1;
        ws[OFF_EW1 + idx] = pack2(ew1[(2 * kk) * 64 + j], ew1[(2 * kk + 1) * 64 + j]);
    }
    // enc2 A-frags: A = W2^T (M=32 feats, K=64 in-feats). k-slot bijection
    // c(q,j) = 32kt + 4q + (j&3) + 16*(j>>2), shared with B-staging in main.
    for (int idx = t; idx < 1024; idx += 256) {
        int r = idx & 3, l = (idx >> 2) & 63, f = idx >> 8;
        int mt = f >> 1, kt = f & 1, q = l >> 4, m = (l & 15) + 16 * mt;
        int j0 = 2 * r;
        int c0 = 32 * kt + 4 * q + (j0 & 3) + 16 * (j0 >> 2);
        ws[OFF_A + idx] = pack2(ew2[c0 * 32 + m], ew2[(c0 + 1) * 32 + m]);
    }
    // enc2 bias in C-layout: feat = 16mt + 4*(l>>4) + reg
    for (int idx = t; idx < 512; idx += 256) {
        int r = idx & 3, l = (idx >> 2) & 63, mt = idx >> 8;
        union { float f; unsigned u; } cvt;
        cvt.f = eb2[16 * mt + 4 * (l >> 4) + r];
        ws[OFF_B2I + idx] = cvt.u;
    }
    // folded encoder tail: Wf = ew3(32,8) @ pw(8,3) -> (32,3), pairs over k
    for (int idx = t; idx < 48; idx += 256) {
        int j = idx >> 4, kk = idx & 15;
        float w0 = 0.f, w1 = 0.f;
        for (int c = 0; c < 8; ++c) {
            w0 += ew3[(2 * kk) * 8 + c] * pw[c * 3 + j];
            w1 += ew3[(2 * kk + 1) * 8 + c] * pw[c * 3 + j];
        }
        ws[OFF_ENCF + idx] = pack2(w0, w1);
    }
    if (t < 3) {
        float b = pb[t];
        for (int c = 0; c < 8; ++c) b += eb3[c] * pw[c * 3 + t];
        union { float f; unsigned u; } cvt; cvt.f = b;
        ws[OFF_ENCFB + t] = cvt.u;
    }
    // flow hidden weights: pack (wh[l][0][j], odd j ? wh[l][1][j] : 0)
    for (int idx = t; idx < 320; idx += 256) {
        int l = idx >> 5, j = idx & 31;
        float w0 = fwh[l * 96 + 0 * 32 + j];
        float w1 = (j & 1) ? fwh[l * 96 + 1 * 32 + j] : 0.0f;
        ws[OFF_FWH + idx] = pack2(w0, w1);
    }
    // flow output weights: even-k dense packing for out-1 (MADE mask), pairs for out-2
    for (int idx = t; idx < 80; idx += 256) {
        int l = idx >> 3, p = idx & 7;
        ws[OFF_FMU1E + idx] = pack2(fwmu[l * 96 + (4 * p) * 3 + 1],
                                    fwmu[l * 96 + (4 * p + 2) * 3 + 1]);
        ws[OFF_FA1E + idx]  = pack2(fwa [l * 96 + (4 * p) * 3 + 1],
                                    fwa [l * 96 + (4 * p + 2) * 3 + 1]);
    }
    for (int idx = t; idx < 160; idx += 256) {
        int l = idx >> 4, kk = idx & 15;
        ws[OFF_FMU2 + idx] = pack2(fwmu[l * 96 + (2 * kk) * 3 + 2],
                                   fwmu[l * 96 + (2 * kk + 1) * 3 + 2]);
        ws[OFF_FA2 + idx]  = pack2(fwa [l * 96 + (2 * kk) * 3 + 2],
                                   fwa [l * 96 + (2 * kk + 1) * 3 + 2]);
    }
    if (t < 10) {
        union { float f; unsigned u; } cvt;
        cvt.f = expf(-tanhf(fba[t * 3 + 0]));
        ws[OFF_C0 + t] = cvt.u;
    }
}

__device__ __forceinline__ float fast_rcp(float x) { return __builtin_amdgcn_rcpf(x); }

__device__ __forceinline__ float fast_tanh(float x) {
    float ax = fabsf(x);
    float t = __expf(-2.0f * ax);
    float r = (1.0f - t) * fast_rcp(1.0f + t);
    return copysignf(r, x);
}

__device__ __forceinline__ unsigned relu2u(float a, float b) {
    half2_t p = __builtin_amdgcn_cvt_pkrtz(a, b);
    half2_t z = {0, 0};
    union { half2_t h; unsigned u; } cvt;
    cvt.h = __builtin_elementwise_max(p, z);
    return cvt.u;
}

__device__ __forceinline__ half2_t relu2h(float a, float b) {
    half2_t p = __builtin_amdgcn_cvt_pkrtz(a, b);
    half2_t z = {0, 0};
    return __builtin_elementwise_max(p, z);
}

// (lo.h0, hi.h0) — extract even elements from two adjacent half2 pairs
__device__ __forceinline__ half2_t evens(half2_t lo, half2_t hi) {
    union { half2_t h; unsigned u; } a, b, r;
    a.h = hi; b.h = lo;
    r.u = __builtin_amdgcn_perm(a.u, b.u, 0x05040100u);
    return r.h;
}

__global__ __launch_bounds__(256)
void gsi_kernel(const float* __restrict__ states,
                const float* __restrict__ eb1,
                const float* __restrict__ fbh, const float* __restrict__ fbmu,
                const float* __restrict__ fba,
                const unsigned* __restrict__ ws,
                float* __restrict__ out, int n, int nhalf)
{
    __shared__ unsigned smem[4 * WAVE_SLICE / 4];

    int i0 = blockIdx.x * blockDim.x + threadIdx.x;   // row set A
    int lane = threadIdx.x & 63;
    int wid = threadIdx.x >> 6;
    bool gA = i0 < nhalf;
    bool gB = (i0 + nhalf) < n;
    int icA = gA ? i0 : 0;
    int icB = gB ? (i0 + nhalf) : 0;

    char* base = (char*)smem + wid * WAVE_SLICE;

    const half2_t* ew1p  = (const half2_t*)(ws + OFF_EW1);
    const half8_t* afr   = (const half8_t*)(ws + OFF_A);
    const f32x4*   b2i   = (const f32x4*)  (ws + OFF_B2I);
    const half2_t* encfp = (const half2_t*)(ws + OFF_ENCF);
    const float*   encfb = (const float*)  (ws + OFF_ENCFB);
    const half2_t* whp   = (const half2_t*)(ws + OFF_FWH);
    const half2_t* mu1ep = (const half2_t*)(ws + OFF_FMU1E);
    const half2_t* a1ep  = (const half2_t*)(ws + OFF_FA1E);
    const half2_t* mu2p  = (const half2_t*)(ws + OFF_FMU2);
    const half2_t* a2p   = (const half2_t*)(ws + OFF_FA2);
    const float*   c0s   = (const float*)  (ws + OFF_C0);

    int q = lane >> 4;
    int l15 = lane & 15;

    // A-frags + bias-init (per-lane VMEM, L2-hot)
    half8_t aF[4];
#pragma unroll
    for (int f = 0; f < 4; ++f) aF[f] = afr[f * 64 + lane];
    f32x4 binit[2];
    binit[0] = b2i[lane];
    binit[1] = b2i[64 + lane];

    float x0[2], x1[2], x2[2];

    // ================== encoder (twice, reusing LDS slice) ==================
#pragma unroll
    for (int r = 0; r < 2; ++r) {
        const float4 s = reinterpret_cast<const float4*>(states)[r == 0 ? icA : icB];
        half2_t s01 = __builtin_amdgcn_cvt_pkrtz(s.x, s.y);
        half2_t s23 = __builtin_amdgcn_cvt_pkrtz(s.z, s.w);

        f32x4 acc[2][4];
#pragma unroll
        for (int mt = 0; mt < 2; ++mt)
#pragma unroll
            for (int nt = 0; nt < 4; ++nt) acc[mt][nt] = binit[mt];

        // enc1 (4->64 dot2) staged to LDS as H1^T; enc2 via MFMA, K in 2 halves
#pragma unroll
        for (int kt = 0; kt < 2; ++kt) {
#pragma unroll
            for (int u = 0; u < 8; ++u) {
                int p0 = kt * 16 + 2 * u;
                float a0 = __builtin_amdgcn_fdot2(s01, ew1p[(2 * p0) * 2 + 0], eb1[2 * p0], false);
                a0 = __builtin_amdgcn_fdot2(s23, ew1p[(2 * p0) * 2 + 1], a0, false);
                float a1 = __builtin_amdgcn_fdot2(s01, ew1p[(2 * p0 + 1) * 2 + 0], eb1[2 * p0 + 1], false);
                a1 = __builtin_amdgcn_fdot2(s23, ew1p[(2 * p0 + 1) * 2 + 1], a1, false);
                float b0 = __builtin_amdgcn_fdot2(s01, ew1p[(2 * p0 + 2) * 2 + 0], eb1[2 * p0 + 2], false);
                b0 = __builtin_amdgcn_fdot2(s23, ew1p[(2 * p0 + 2) * 2 + 1], b0, false);
                float b1 = __builtin_amdgcn_fdot2(s01, ew1p[(2 * p0 + 3) * 2 + 0], eb1[2 * p0 + 3], false);
                b1 = __builtin_amdgcn_fdot2(s23, ew1p[(2 * p0 + 3) * 2 + 1], b1, false);
                u32x2 wv;
                wv.x = relu2u(a0, a1);
                wv.y = relu2u(b0, b1);
                *(u32x2*)(base + lane * ROW_STRIDE + 8 * u) = wv;
            }
#pragma unroll
            for (int nt = 0; nt < 4; ++nt) {
                u32x2 r0 = *(const u32x2*)(base + (16 * nt + l15) * ROW_STRIDE + 8 * (q + 0));
                u32x2 r1 = *(const u32x2*)(base + (16 * nt + l15) * ROW_STRIDE + 8 * (q + 4));
                union { unsigned u[4]; half8_t v; } bb;
                bb.u[0] = r0.x; bb.u[1] = r0.y; bb.u[2] = r1.x; bb.u[3] = r1.y;
#pragma unroll
                for (int mt = 0; mt < 2; ++mt) {
                    acc[mt][nt] = __builtin_amdgcn_mfma_f32_16x16x32_f16(
                        aF[mt * 2 + kt], bb.v, acc[mt][nt], 0, 0, 0);
                }
            }
        }

        // relu + pack H2^T back to per-thread layout via LDS
#pragma unroll
        for (int mt = 0; mt < 2; ++mt) {
#pragma unroll
            for (int nt = 0; nt < 4; ++nt) {
                f32x4 v = acc[mt][nt];
                u32x2 wv;
                wv.x = relu2u(v[0], v[1]);
                wv.y = relu2u(v[2], v[3]);
                *(u32x2*)(base + (16 * nt + l15) * ROW_STRIDE + 8 * (q + 4 * mt)) = wv;
            }
        }
        // folded tail 32 -> 3 (features are sequential in d)
        float t0 = encfb[0], t1 = encfb[1], t2 = encfb[2];
#pragma unroll
        for (int d = 0; d < 8; ++d) {
            u32x2 v = *(const u32x2*)(base + lane * ROW_STRIDE + 8 * d);
            union { unsigned u; half2_t h; } c0, c1;
            c0.u = v.x; c1.u = v.y;
            t0 = __builtin_amdgcn_fdot2(c0.h, encfp[0 * 16 + 2 * d], t0, false);
            t1 = __builtin_amdgcn_fdot2(c0.h, encfp[1 * 16 + 2 * d], t1, false);
            t2 = __builtin_amdgcn_fdot2(c0.h, encfp[2 * 16 + 2 * d], t2, false);
            t0 = __builtin_amdgcn_fdot2(c1.h, encfp[0 * 16 + 2 * d + 1], t0, false);
            t1 = __builtin_amdgcn_fdot2(c1.h, encfp[1 * 16 + 2 * d + 1], t1, false);
            t2 = __builtin_amdgcn_fdot2(c1.h, encfp[2 * 16 + 2 * d + 1], t2, false);
        }
        x0[r] = t0; x1[r] = t1; x2[r] = t2;
    }

    // ================== MAF flow: 10 layers, 2 rows interleaved ==================
#pragma unroll
    for (int l = 0; l < 10; ++l) {
        half2_t xp[2];
#pragma unroll
        for (int r = 0; r < 2; ++r) xp[r] = __builtin_amdgcn_cvt_pkrtz(x0[r], x1[r]);

        float bm1 = fbmu[l * 3 + 1], bm2 = fbmu[l * 3 + 2];
        float bb1 = fba[l * 3 + 1],  bb2 = fba[l * 3 + 2];
        float mu1[2] = {bm1, bm1}, mu2[2] = {bm2, bm2};
        float aa1[2] = {bb1, bb1}, aa2[2] = {bb2, bb2};

#pragma unroll
        for (int p = 0; p < 8; ++p) {
#pragma unroll
            for (int r = 0; r < 2; ++r) {
                float a0 = __builtin_amdgcn_fdot2(xp[r], whp[l * 32 + 4 * p + 0], fbh[l * 32 + 4 * p + 0], false);
                float a1 = __builtin_amdgcn_fdot2(xp[r], whp[l * 32 + 4 * p + 1], fbh[l * 32 + 4 * p + 1], false);
                float b0 = __builtin_amdgcn_fdot2(xp[r], whp[l * 32 + 4 * p + 2], fbh[l * 32 + 4 * p + 2], false);
                float b1 = __builtin_amdgcn_fdot2(xp[r], whp[l * 32 + 4 * p + 3], fbh[l * 32 + 4 * p + 3], false);
                half2_t ha = relu2h(a0, a1);   // h[4p], h[4p+1]
                half2_t hb = relu2h(b0, b1);   // h[4p+2], h[4p+3]
                mu2[r] = __builtin_amdgcn_fdot2(ha, mu2p[l * 16 + 2 * p], mu2[r], false);
                aa2[r] = __builtin_amdgcn_fdot2(ha, a2p[l * 16 + 2 * p], aa2[r], false);
                mu2[r] = __builtin_amdgcn_fdot2(hb, mu2p[l * 16 + 2 * p + 1], mu2[r], false);
                aa2[r] = __builtin_amdgcn_fdot2(hb, a2p[l * 16 + 2 * p + 1], aa2[r], false);
                half2_t e = evens(ha, hb);     // h[4p], h[4p+2]
                mu1[r] = __builtin_amdgcn_fdot2(e, mu1ep[l * 8 + p], mu1[r], false);
                aa1[r] = __builtin_amdgcn_fdot2(e, a1ep[l * 8 + p], aa1[r], false);
            }
        }

        float bm0 = fbmu[l * 3 + 0];
        float c0l = c0s[l];
#pragma unroll
        for (int r = 0; r < 2; ++r) {
            float t1 = fast_tanh(aa1[r]);
            float t2 = fast_tanh(aa2[r]);
            float y0 = (x0[r] - bm0) * c0l;
            float y1 = (x1[r] - mu1[r]) * __expf(-t1);
            float y2 = (x2[r] - mu2[r]) * __expf(-t2);
            x0[r] = y2; x1[r] = y1; x2[r] = y0;
        }
    }

    // ================== squash + HSV + store ==================
#pragma unroll
    for (int r = 0; r < 2; ++r) {
        float u0 = fast_rcp(1.0f + __expf(-x0[r]));
        float u1 = fast_rcp(1.0f + __expf(-x1[r]));
        float u2 = fast_rcp(1.0f + __expf(-x2[r]));
        bool g = (r == 0) ? gA : gB;
        int idx = (r == 0) ? i0 : (i0 + nhalf);
        if (g) {
            out[3 * idx + 0] = TWO_PI_F * u0;
            out[3 * idx + 1] = u1;
            out[3 * idx + 2] = u2;
        }
    }
}

extern "C" void kernel_launch(void* const* d_in, const int* in_sizes, int n_in,
                              void* d_out, int out_size, void* d_ws, size_t ws_size,
                              hipStream_t stream) {
    const float* states = (const float*)d_in[0];
    const float* ew1  = (const float*)d_in[1];
    const float* eb1  = (const float*)d_in[2];
    const float* ew2  = (const float*)d_in[3];
    const float* eb2  = (const float*)d_in[4];
    const float* ew3  = (const float*)d_in[5];
    const float* eb3  = (const float*)d_in[6];
    const float* pw   = (const float*)d_in[7];
    const float* pb   = (const float*)d_in[8];
    const float* fwh  = (const float*)d_in[9];
    const float* fbh  = (const float*)d_in[10];
    const float* fwmu = (const float*)d_in[11];
    const float* fbmu = (const float*)d_in[12];
    const float* fwa  = (const float*)d_in[13];
    const float* fba  = (const float*)d_in[14];
    float* out = (float*)d_out;
    unsigned* ws = (unsigned*)d_ws;

    gsi_setup<<<1, 256, 0, stream>>>(ew1, ew2, eb2, ew3, eb3, pw, pb,
                                     fwh, fwmu, fwa, fba, ws);

    int n = in_sizes[0] / 4;
    int nhalf = (n + 1) / 2;
    int grid = (nhalf + 255) / 256;
    gsi_kernel<<<grid, 256, 0, stream>>>(states, eb1, fbh, fbmu, fba, ws, out, n, nhalf);
}

// Round 6
// 131.236 us; speedup vs baseline: 2.0163x; 2.0163x over previous
//
#include <hip/hip_runtime.h>
#include <math.h>

#define TWO_PI_F 6.283185307179586f

typedef __fp16 half2_t __attribute__((ext_vector_type(2)));
typedef __fp16 half8_t __attribute__((ext_vector_type(8)));
typedef float  f32x4   __attribute__((ext_vector_type(4)));
typedef unsigned u32x2 __attribute__((ext_vector_type(2)));

// ---- d_ws layout (u32 units) ----
#define OFF_A1C   0      // [4 t][16 m15][2]  enc1 A compact: pack(W1[0/2][f],W1[1/3][f])
#define OFF_A2    128    // [4 (mt*2+kt)][64 lane][4 reg] enc2 A-frags
#define OFF_ATL   1152   // [64 lane][4 reg]  tail A-frag (Wf^T, rows>=3 zero)
#define OFF_ENCFB 1408   // [3] f32 folded tail bias (eb3@pw + pb)
#define OFF_FWH   1412   // [10][32]  (wh[l][0][j], odd j? wh[l][1][j]:0) pairs
#define OFF_FMU1  1732   // [10][16]  masked wmu[:,1] pairs (odd slot zero)
#define OFF_FMU2  1892   // [10][16]  wmu[:,2] pairs
#define OFF_FA1   2052   // [10][16]  masked wa[:,1] pairs
#define OFF_FA2   2212   // [10][16]  wa[:,2] pairs
#define OFF_C0    2372   // [10] f32  exp(-tanh(ba[l][0]))
// total 2382 u32

__device__ __forceinline__ unsigned pack2(float a, float b) {
    half2_t h = __builtin_amdgcn_cvt_pkrtz(a, b);
    union { half2_t h; unsigned u; } cvt;
    cvt.h = h;
    return cvt.u;
}

__global__ __launch_bounds__(256)
void gsi_setup(const float* __restrict__ ew1, const float* __restrict__ ew2,
               const float* __restrict__ ew3, const float* __restrict__ eb3,
               const float* __restrict__ pw,  const float* __restrict__ pb,
               const float* __restrict__ fwh, const float* __restrict__ fwmu,
               const float* __restrict__ fwa, const float* __restrict__ fba,
               unsigned* __restrict__ ws)
{
    int t = threadIdx.x;

    // enc1 A compact: [t][m15][h]: pack(W1[2h][16t+m15], W1[2h+1][16t+m15])
    for (int idx = t; idx < 128; idx += 256) {
        int tt = idx >> 5, rest = idx & 31, m15 = rest >> 1, h = rest & 1;
        int f = 16 * tt + m15;
        ws[OFF_A1C + idx] = pack2(ew1[(2 * h) * 64 + f], ew1[(2 * h + 1) * 64 + f]);
    }
    // enc2 A-frags: A = W2^T (M=32 feats, K=64). k-slot bijection
    // c(q,j) = 32kt + 4q + (j&3) + 16*(j>>2)  (identical to R4 — bit-exact verified)
    for (int idx = t; idx < 1024; idx += 256) {
        int r = idx & 3, l = (idx >> 2) & 63, f = idx >> 8;
        int mt = f >> 1, kt = f & 1, q = l >> 4, m = (l & 15) + 16 * mt;
        int j0 = 2 * r;
        int c0 = 32 * kt + 4 * q + (j0 & 3) + 16 * (j0 >> 2);
        ws[OFF_A2 + idx] = pack2(ew2[c0 * 32 + m], ew2[(c0 + 1) * 32 + m]);
    }
    // tail A-frag: Wf = ew3(32,8)@pw(8,3); A[m15][k=c(q,j)] = Wf[k][m15], m15<3
    for (int idx = t; idx < 256; idx += 256) {
        int lane = idx >> 2, r = idx & 3;
        int q = lane >> 4, m15 = lane & 15;
        unsigned v = 0;
        if (m15 < 3) {
            int j0 = 2 * r, j1 = 2 * r + 1;
            int k0 = 4 * q + (j0 & 3) + 16 * (j0 >> 2);
            int k1 = 4 * q + (j1 & 3) + 16 * (j1 >> 2);
            float w0 = 0.f, w1 = 0.f;
            for (int c = 0; c < 8; ++c) {
                w0 += ew3[k0 * 8 + c] * pw[c * 3 + m15];
                w1 += ew3[k1 * 8 + c] * pw[c * 3 + m15];
            }
            v = pack2(w0, w1);
        }
        ws[OFF_ATL + idx] = v;
    }
    // folded tail bias: eb3 @ pw + pb
    if (t < 3) {
        float b = pb[t];
        for (int c = 0; c < 8; ++c) b += eb3[c] * pw[c * 3 + t];
        union { float f; unsigned u; } cvt; cvt.f = b;
        ws[OFF_ENCFB + t] = cvt.u;
    }
    // flow hidden weights: pack (wh[l][0][j], odd j ? wh[l][1][j] : 0)
    for (int idx = t; idx < 320; idx += 256) {
        int l = idx >> 5, j = idx & 31;
        float w0 = fwh[l * 96 + 0 * 32 + j];
        float w1 = (j & 1) ? fwh[l * 96 + 1 * 32 + j] : 0.0f;
        ws[OFF_FWH + idx] = pack2(w0, w1);
    }
    // flow output weights with MADE masks folded
    for (int idx = t; idx < 160; idx += 256) {
        int l = idx >> 4, kk = idx & 15;
        ws[OFF_FMU1 + idx] = pack2(fwmu[l * 96 + (2 * kk) * 3 + 1], 0.0f);
        ws[OFF_FA1  + idx] = pack2(fwa [l * 96 + (2 * kk) * 3 + 1], 0.0f);
        ws[OFF_FMU2 + idx] = pack2(fwmu[l * 96 + (2 * kk) * 3 + 2],
                                   fwmu[l * 96 + (2 * kk + 1) * 3 + 2]);
        ws[OFF_FA2  + idx] = pack2(fwa [l * 96 + (2 * kk) * 3 + 2],
                                   fwa [l * 96 + (2 * kk + 1) * 3 + 2]);
    }
    if (t < 10) {
        union { float f; unsigned u; } cvt;
        cvt.f = expf(-tanhf(fba[t * 3 + 0]));
        ws[OFF_C0 + t] = cvt.u;
    }
}

__device__ __forceinline__ float fast_rcp(float x) { return __builtin_amdgcn_rcpf(x); }

__device__ __forceinline__ float fast_tanh(float x) {
    float ax = fabsf(x);
    float t = __expf(-2.0f * ax);
    float r = (1.0f - t) * fast_rcp(1.0f + t);
    return copysignf(r, x);
}

__device__ __forceinline__ unsigned relu2u(float a, float b) {
    half2_t p = __builtin_amdgcn_cvt_pkrtz(a, b);
    half2_t z = {0, 0};
    union { half2_t h; unsigned u; } cvt;
    cvt.h = __builtin_elementwise_max(p, z);
    return cvt.u;
}

__device__ __forceinline__ half8_t mk8(unsigned a, unsigned b, unsigned c, unsigned d) {
    union { unsigned u[4]; half8_t v; } r;
    r.u[0] = a; r.u[1] = b; r.u[2] = c; r.u[3] = d;
    return r.v;
}

__global__ __launch_bounds__(256)
void gsi_kernel(const float* __restrict__ states,
                const float* __restrict__ eb1, const float* __restrict__ eb2,
                const float* __restrict__ fbh, const float* __restrict__ fbmu,
                const float* __restrict__ fba,
                const unsigned* __restrict__ ws,
                float* __restrict__ out, int n)
{
    int i = blockIdx.x * blockDim.x + threadIdx.x;
    int lane = threadIdx.x & 63;
    int wid = threadIdx.x >> 6;
    int rowbase = blockIdx.x * 256 + wid * 64;
    int q = lane >> 4;
    int l15 = lane & 15;
    bool q0 = (q == 0);

    const half8_t* a2p8 = (const half8_t*)(ws + OFF_A2);
    const float*   encfb = (const float*)(ws + OFF_ENCFB);
    const half2_t* whp   = (const half2_t*)(ws + OFF_FWH);
    const half2_t* mu1p  = (const half2_t*)(ws + OFF_FMU1);
    const half2_t* mu2p  = (const half2_t*)(ws + OFF_FMU2);
    const half2_t* a1p   = (const half2_t*)(ws + OFF_FA1);
    const half2_t* a2wp  = (const half2_t*)(ws + OFF_FA2);
    const float*   c0s   = (const float*)(ws + OFF_C0);

    // ---- persistent fragments ----
    // enc1 A: tile t, lane (q,m15): nonzero only q==0, regs {0,1}
    half8_t aF1[4];
#pragma unroll
    for (int t = 0; t < 4; ++t) {
        u32x2 c = *(const u32x2*)(ws + OFF_A1C + t * 32 + l15 * 2);
        aF1[t] = mk8(q0 ? c.x : 0u, q0 ? c.y : 0u, 0u, 0u);
    }
    // enc2 A
    half8_t aF2[4];
#pragma unroll
    for (int f = 0; f < 4; ++f) aF2[f] = a2p8[f * 64 + lane];
    // tail A
    half8_t aFt = a2p8[4 * 64 + lane];   // OFF_ATL == OFF_A2 + 4*64*4 u32

    // bias C-inits (vector-aligned direct loads)
    f32x4 eb1c[4];
#pragma unroll
    for (int t = 0; t < 4; ++t) eb1c[t] = *(const f32x4*)(eb1 + 16 * t + 4 * q);
    f32x4 eb2c[2];
#pragma unroll
    for (int mt = 0; mt < 2; ++mt) eb2c[mt] = *(const f32x4*)(eb2 + 16 * mt + 4 * q);
    f32x4 tbias;
    {
        float e0 = encfb[0], e1 = encfb[1], e2 = encfb[2];
        tbias[0] = q0 ? e0 : 0.f;
        tbias[1] = q0 ? e1 : 0.f;
        tbias[2] = q0 ? e2 : 0.f;
        tbias[3] = 0.f;
    }

    // ================== encoder: all-MFMA, no LDS ==================
    f32x4 acct[4];
#pragma unroll
    for (int nt = 0; nt < 4; ++nt) {
        // B1: states^T fragment for rows 16nt + l15 (K=4 in slots 0..3, q==0 only)
        int row = rowbase + 16 * nt + l15;
        row = row < n ? row : (n - 1);
        const float4 s = reinterpret_cast<const float4*>(states)[row];
        unsigned p01 = pack2(s.x, s.y);
        unsigned p23 = pack2(s.z, s.w);
        half8_t b1 = mk8(q0 ? p01 : 0u, q0 ? p23 : 0u, 0u, 0u);

        // enc1: 4 m-tiles, K=32 (real 4)
        f32x4 acc1[4];
#pragma unroll
        for (int t = 0; t < 4; ++t)
            acc1[t] = __builtin_amdgcn_mfma_f32_16x16x32_f16(aF1[t], b1, eb1c[t], 0, 0, 0);

        // relu+pack: C-regs ARE the next B-frags (feature 16t+4q+reg == k-slot c(q,j))
        half8_t b2f0 = mk8(relu2u(acc1[0][0], acc1[0][1]), relu2u(acc1[0][2], acc1[0][3]),
                           relu2u(acc1[1][0], acc1[1][1]), relu2u(acc1[1][2], acc1[1][3]));
        half8_t b2f1 = mk8(relu2u(acc1[2][0], acc1[2][1]), relu2u(acc1[2][2], acc1[2][3]),
                           relu2u(acc1[3][0], acc1[3][1]), relu2u(acc1[3][2], acc1[3][3]));

        // enc2: 2 m-tiles x 2 kt
        f32x4 acc2[2];
#pragma unroll
        for (int mt = 0; mt < 2; ++mt) {
            f32x4 a = __builtin_amdgcn_mfma_f32_16x16x32_f16(aF2[mt * 2 + 0], b2f0, eb2c[mt], 0, 0, 0);
            acc2[mt] = __builtin_amdgcn_mfma_f32_16x16x32_f16(aF2[mt * 2 + 1], b2f1, a, 0, 0, 0);
        }

        // relu+pack -> tail B-frag
        half8_t btl = mk8(relu2u(acc2[0][0], acc2[0][1]), relu2u(acc2[0][2], acc2[0][3]),
                          relu2u(acc2[1][0], acc2[1][1]), relu2u(acc2[1][2], acc2[1][3]));

        // tail: 32 -> 3 (one m-tile, rows >= 3 zero)
        acct[nt] = __builtin_amdgcn_mfma_f32_16x16x32_f16(aFt, btl, tbias, 0, 0, 0);
    }

    // redistribute: row (16nt+l15)'s x_m sits in lane l15, acct[nt][m]
    float x0, x1, x2;
    {
        int paddr = l15 * 4;
        float xr[3];
#pragma unroll
        for (int m = 0; m < 3; ++m) {
            float p0 = __int_as_float(__builtin_amdgcn_ds_bpermute(paddr, __float_as_int(acct[0][m])));
            float p1 = __int_as_float(__builtin_amdgcn_ds_bpermute(paddr, __float_as_int(acct[1][m])));
            float p2 = __int_as_float(__builtin_amdgcn_ds_bpermute(paddr, __float_as_int(acct[2][m])));
            float p3 = __int_as_float(__builtin_amdgcn_ds_bpermute(paddr, __float_as_int(acct[3][m])));
            float lo = (lane & 32) ? p2 : p0;
            float hi = (lane & 32) ? p3 : p1;
            xr[m] = (lane & 16) ? hi : lo;
        }
        x0 = xr[0]; x1 = xr[1]; x2 = xr[2];
    }

    // ================== MAF flow (verbatim R4 structure) ==================
#pragma unroll
    for (int l = 0; l < 10; ++l) {
        half2_t xp = __builtin_amdgcn_cvt_pkrtz(x0, x1);
        half2_t hp[16];
#pragma unroll
        for (int j = 0; j < 16; ++j) {
            float a0 = __builtin_amdgcn_fdot2(xp, whp[l * 32 + 2 * j],     fbh[l * 32 + 2 * j],     false);
            float a1 = __builtin_amdgcn_fdot2(xp, whp[l * 32 + 2 * j + 1], fbh[l * 32 + 2 * j + 1], false);
            half2_t p = __builtin_amdgcn_cvt_pkrtz(a0, a1);
            half2_t z = {0, 0};
            hp[j] = __builtin_elementwise_max(p, z);
        }
        float mu1 = fbmu[l * 3 + 1], mu2 = fbmu[l * 3 + 2];
        float aa1 = fba[l * 3 + 1],  aa2 = fba[l * 3 + 2];
#pragma unroll
        for (int kk = 0; kk < 16; ++kk) {
            mu1 = __builtin_amdgcn_fdot2(hp[kk], mu1p[l * 16 + kk], mu1, false);
            mu2 = __builtin_amdgcn_fdot2(hp[kk], mu2p[l * 16 + kk], mu2, false);
            aa1 = __builtin_amdgcn_fdot2(hp[kk], a1p[l * 16 + kk], aa1, false);
            aa2 = __builtin_amdgcn_fdot2(hp[kk], a2wp[l * 16 + kk], aa2, false);
        }
        float t1 = fast_tanh(aa1);
        float t2 = fast_tanh(aa2);
        float y0 = (x0 - fbmu[l * 3 + 0]) * c0s[l];
        float y1 = (x1 - mu1) * __expf(-t1);
        float y2 = (x2 - mu2) * __expf(-t2);
        x0 = y2; x1 = y1; x2 = y0;
    }

    // ================== squash + HSV ==================
    float u0 = fast_rcp(1.0f + __expf(-x0));
    float u1 = fast_rcp(1.0f + __expf(-x1));
    float u2 = fast_rcp(1.0f + __expf(-x2));

    if (i < n) {
        out[3 * i + 0] = TWO_PI_F * u0;
        out[3 * i + 1] = u1;
        out[3 * i + 2] = u2;
    }
}

extern "C" void kernel_launch(void* const* d_in, const int* in_sizes, int n_in,
                              void* d_out, int out_size, void* d_ws, size_t ws_size,
                              hipStream_t stream) {
    const float* states = (const float*)d_in[0];
    const float* ew1  = (const float*)d_in[1];
    const float* eb1  = (const float*)d_in[2];
    const float* ew2  = (const float*)d_in[3];
    const float* eb2  = (const float*)d_in[4];
    const float* ew3  = (const float*)d_in[5];
    const float* eb3  = (const float*)d_in[6];
    const float* pw   = (const float*)d_in[7];
    const float* pb   = (const float*)d_in[8];
    const float* fwh  = (const float*)d_in[9];
    const float* fbh  = (const float*)d_in[10];
    const float* fwmu = (const float*)d_in[11];
    const float* fbmu = (const float*)d_in[12];
    const float* fwa  = (const float*)d_in[13];
    const float* fba  = (const float*)d_in[14];
    float* out = (float*)d_out;
    unsigned* ws = (unsigned*)d_ws;

    gsi_setup<<<1, 256, 0, stream>>>(ew1, ew2, ew3, eb3, pw, pb,
                                     fwh, fwmu, fwa, fba, ws);

    int n = in_sizes[0] / 4;
    int grid = (n + 255) / 256;
    gsi_kernel<<<grid, 256, 0, stream>>>(states, eb1, eb2, fbh, fbmu, fba, ws, out, n);
}

// Round 7
// 110.709 us; speedup vs baseline: 2.3902x; 1.1854x over previous
//
#include <hip/hip_runtime.h>
#include <math.h>

#define TWO_PI_F 6.283185307179586f

typedef __fp16 half2_t __attribute__((ext_vector_type(2)));
typedef __fp16 half8_t __attribute__((ext_vector_type(8)));
typedef float  f32x4   __attribute__((ext_vector_type(4)));
typedef unsigned u32x2 __attribute__((ext_vector_type(2)));

// ---- d_ws layout (u32 units) ----
#define OFF_A1C   0      // [4 t][16 m15][2]  enc1 A compact
#define OFF_A2    128    // [4 (mt*2+kt)][64 lane][4 reg] enc2 A-frags
#define OFF_ATL   1152   // [64 lane][4 reg]  tail A-frag (Wf^T, rows>=3 zero)
#define OFF_ENCFB 1408   // [3] f32 folded tail bias
#define OFF_FL    1424   // [10][112] per-layer flow block (16-aligned):
//   +0   w0 pairs  [16]  (wh[0][2j], wh[0][2j+1])
//   +16  w1 pairs  [16]  (0, wh[1][2j+1])          (MADE mask folded)
//   +32  bh pairs  [16]
//   +48  mu2 pairs [16]  (wmu[2k][2], wmu[2k+1][2])
//   +64  a2  pairs [16]
//   +80  mu1 even  [8]   (wmu[4p][1], wmu[4p+2][1])
//   +88  a1  even  [8]
//   +96  f32 scalars: bm0,bm1,bm2,bb1,bb2,c0  (+pad to 112)
// total 1424 + 1120 = 2544 u32

__device__ __forceinline__ unsigned pack2(float a, float b) {
    half2_t h = __builtin_amdgcn_cvt_pkrtz(a, b);
    union { half2_t h; unsigned u; } cvt;
    cvt.h = h;
    return cvt.u;
}

__global__ __launch_bounds__(256)
void gsi_setup(const float* __restrict__ ew1, const float* __restrict__ ew2,
               const float* __restrict__ ew3, const float* __restrict__ eb3,
               const float* __restrict__ pw,  const float* __restrict__ pb,
               const float* __restrict__ fwh, const float* __restrict__ fbh,
               const float* __restrict__ fwmu, const float* __restrict__ fbmu,
               const float* __restrict__ fwa, const float* __restrict__ fba,
               unsigned* __restrict__ ws)
{
    int t = threadIdx.x;

    // enc1 A compact: [t][m15][h]: pack(W1[2h][16t+m15], W1[2h+1][16t+m15])
    for (int idx = t; idx < 128; idx += 256) {
        int tt = idx >> 5, rest = idx & 31, m15 = rest >> 1, h = rest & 1;
        int f = 16 * tt + m15;
        ws[OFF_A1C + idx] = pack2(ew1[(2 * h) * 64 + f], ew1[(2 * h + 1) * 64 + f]);
    }
    // enc2 A-frags: c(q,j) = 32kt + 4q + (j&3) + 16*(j>>2)
    for (int idx = t; idx < 1024; idx += 256) {
        int r = idx & 3, l = (idx >> 2) & 63, f = idx >> 8;
        int mt = f >> 1, kt = f & 1, q = l >> 4, m = (l & 15) + 16 * mt;
        int j0 = 2 * r;
        int c0 = 32 * kt + 4 * q + (j0 & 3) + 16 * (j0 >> 2);
        ws[OFF_A2 + idx] = pack2(ew2[c0 * 32 + m], ew2[(c0 + 1) * 32 + m]);
    }
    // tail A-frag: Wf = ew3(32,8)@pw(8,3)
    for (int idx = t; idx < 256; idx += 256) {
        int lane = idx >> 2, r = idx & 3;
        int q = lane >> 4, m15 = lane & 15;
        unsigned v = 0;
        if (m15 < 3) {
            int j0 = 2 * r, j1 = 2 * r + 1;
            int k0 = 4 * q + (j0 & 3) + 16 * (j0 >> 2);
            int k1 = 4 * q + (j1 & 3) + 16 * (j1 >> 2);
            float w0 = 0.f, w1 = 0.f;
            for (int c = 0; c < 8; ++c) {
                w0 += ew3[k0 * 8 + c] * pw[c * 3 + m15];
                w1 += ew3[k1 * 8 + c] * pw[c * 3 + m15];
            }
            v = pack2(w0, w1);
        }
        ws[OFF_ATL + idx] = v;
    }
    if (t < 3) {
        float b = pb[t];
        for (int c = 0; c < 8; ++c) b += eb3[c] * pw[c * 3 + t];
        union { float f; unsigned u; } cvt; cvt.f = b;
        ws[OFF_ENCFB + t] = cvt.u;
    }

    // ---- flow per-layer blocks ----
    for (int idx = t; idx < 160; idx += 256) {   // 10 layers x 16 pairs
        int l = idx >> 4, j = idx & 15;
        unsigned* L = ws + OFF_FL + l * 112;
        L[j]      = pack2(fwh[l * 96 + 0 * 32 + 2 * j], fwh[l * 96 + 0 * 32 + 2 * j + 1]);
        L[16 + j] = pack2(0.0f, fwh[l * 96 + 1 * 32 + 2 * j + 1]);
        L[32 + j] = pack2(fbh[l * 32 + 2 * j], fbh[l * 32 + 2 * j + 1]);
        L[48 + j] = pack2(fwmu[l * 96 + (2 * j) * 3 + 2], fwmu[l * 96 + (2 * j + 1) * 3 + 2]);
        L[64 + j] = pack2(fwa [l * 96 + (2 * j) * 3 + 2], fwa [l * 96 + (2 * j + 1) * 3 + 2]);
    }
    for (int idx = t; idx < 80; idx += 256) {    // 10 layers x 8 even-pairs
        int l = idx >> 3, p = idx & 7;
        unsigned* L = ws + OFF_FL + l * 112;
        L[80 + p] = pack2(fwmu[l * 96 + (4 * p) * 3 + 1], fwmu[l * 96 + (4 * p + 2) * 3 + 1]);
        L[88 + p] = pack2(fwa [l * 96 + (4 * p) * 3 + 1], fwa [l * 96 + (4 * p + 2) * 3 + 1]);
    }
    if (t < 10) {
        float* Lf = (float*)(ws + OFF_FL + t * 112 + 96);
        Lf[0] = fbmu[t * 3 + 0];
        Lf[1] = fbmu[t * 3 + 1];
        Lf[2] = fbmu[t * 3 + 2];
        Lf[3] = fba[t * 3 + 1];
        Lf[4] = fba[t * 3 + 2];
        Lf[5] = expf(-tanhf(fba[t * 3 + 0]));
    }
}

__device__ __forceinline__ float fast_rcp(float x) { return __builtin_amdgcn_rcpf(x); }

__device__ __forceinline__ float fast_tanh(float x) {
    float ax = fabsf(x);
    float t = __expf(-2.0f * ax);
    float r = (1.0f - t) * fast_rcp(1.0f + t);
    return copysignf(r, x);
}

__device__ __forceinline__ unsigned relu2u(float a, float b) {
    half2_t p = __builtin_amdgcn_cvt_pkrtz(a, b);
    half2_t z = {0, 0};
    union { half2_t h; unsigned u; } cvt;
    cvt.h = __builtin_elementwise_max(p, z);
    return cvt.u;
}

__device__ __forceinline__ half8_t mk8(unsigned a, unsigned b, unsigned c, unsigned d) {
    union { unsigned u[4]; half8_t v; } r;
    r.u[0] = a; r.u[1] = b; r.u[2] = c; r.u[3] = d;
    return r.v;
}

// (lo.h0, hi.h0) — even elements of two adjacent half2 pairs (bit-exact verified R5)
__device__ __forceinline__ half2_t evens(half2_t lo, half2_t hi) {
    union { half2_t h; unsigned u; } a, b, r;
    a.h = hi; b.h = lo;
    r.u = __builtin_amdgcn_perm(a.u, b.u, 0x05040100u);
    return r.h;
}

__global__ __launch_bounds__(256)
void gsi_kernel(const float* __restrict__ states,
                const float* __restrict__ eb1, const float* __restrict__ eb2,
                const unsigned* __restrict__ ws,
                float* __restrict__ out, int n)
{
    int i = blockIdx.x * blockDim.x + threadIdx.x;
    int lane = threadIdx.x & 63;
    int wid = threadIdx.x >> 6;
    int rowbase = blockIdx.x * 256 + wid * 64;
    int q = lane >> 4;
    int l15 = lane & 15;
    bool q0 = (q == 0);

    const half8_t* a2p8  = (const half8_t*)(ws + OFF_A2);
    const float*   encfb = (const float*)(ws + OFF_ENCFB);

    // ---- persistent fragments ----
    half8_t aF1[4];
#pragma unroll
    for (int t = 0; t < 4; ++t) {
        u32x2 c = *(const u32x2*)(ws + OFF_A1C + t * 32 + l15 * 2);
        aF1[t] = mk8(q0 ? c.x : 0u, q0 ? c.y : 0u, 0u, 0u);
    }
    half8_t aF2[4];
#pragma unroll
    for (int f = 0; f < 4; ++f) aF2[f] = a2p8[f * 64 + lane];
    half8_t aFt = a2p8[4 * 64 + lane];   // OFF_ATL == OFF_A2 + 4*64*4 u32

    f32x4 eb1c[4];
#pragma unroll
    for (int t = 0; t < 4; ++t) eb1c[t] = *(const f32x4*)(eb1 + 16 * t + 4 * q);
    f32x4 eb2c[2];
#pragma unroll
    for (int mt = 0; mt < 2; ++mt) eb2c[mt] = *(const f32x4*)(eb2 + 16 * mt + 4 * q);
    f32x4 tbias;
    {
        float e0 = encfb[0], e1 = encfb[1], e2 = encfb[2];
        tbias[0] = q0 ? e0 : 0.f;
        tbias[1] = q0 ? e1 : 0.f;
        tbias[2] = q0 ? e2 : 0.f;
        tbias[3] = 0.f;
    }

    // ================== encoder: all-MFMA, no LDS (verbatim R6) ==================
    f32x4 acct[4];
#pragma unroll
    for (int nt = 0; nt < 4; ++nt) {
        int row = rowbase + 16 * nt + l15;
        row = row < n ? row : (n - 1);
        const float4 s = reinterpret_cast<const float4*>(states)[row];
        unsigned p01 = pack2(s.x, s.y);
        unsigned p23 = pack2(s.z, s.w);
        half8_t b1 = mk8(q0 ? p01 : 0u, q0 ? p23 : 0u, 0u, 0u);

        f32x4 acc1[4];
#pragma unroll
        for (int t = 0; t < 4; ++t)
            acc1[t] = __builtin_amdgcn_mfma_f32_16x16x32_f16(aF1[t], b1, eb1c[t], 0, 0, 0);

        half8_t b2f0 = mk8(relu2u(acc1[0][0], acc1[0][1]), relu2u(acc1[0][2], acc1[0][3]),
                           relu2u(acc1[1][0], acc1[1][1]), relu2u(acc1[1][2], acc1[1][3]));
        half8_t b2f1 = mk8(relu2u(acc1[2][0], acc1[2][1]), relu2u(acc1[2][2], acc1[2][3]),
                           relu2u(acc1[3][0], acc1[3][1]), relu2u(acc1[3][2], acc1[3][3]));

        f32x4 acc2[2];
#pragma unroll
        for (int mt = 0; mt < 2; ++mt) {
            f32x4 a = __builtin_amdgcn_mfma_f32_16x16x32_f16(aF2[mt * 2 + 0], b2f0, eb2c[mt], 0, 0, 0);
            acc2[mt] = __builtin_amdgcn_mfma_f32_16x16x32_f16(aF2[mt * 2 + 1], b2f1, a, 0, 0, 0);
        }

        half8_t btl = mk8(relu2u(acc2[0][0], acc2[0][1]), relu2u(acc2[0][2], acc2[0][3]),
                          relu2u(acc2[1][0], acc2[1][1]), relu2u(acc2[1][2], acc2[1][3]));

        acct[nt] = __builtin_amdgcn_mfma_f32_16x16x32_f16(aFt, btl, tbias, 0, 0, 0);
    }

    // redistribute x to owner lanes
    float x0, x1, x2;
    {
        int paddr = l15 * 4;
        float xr[3];
#pragma unroll
        for (int m = 0; m < 3; ++m) {
            float p0 = __int_as_float(__builtin_amdgcn_ds_bpermute(paddr, __float_as_int(acct[0][m])));
            float p1 = __int_as_float(__builtin_amdgcn_ds_bpermute(paddr, __float_as_int(acct[1][m])));
            float p2 = __int_as_float(__builtin_amdgcn_ds_bpermute(paddr, __float_as_int(acct[2][m])));
            float p3 = __int_as_float(__builtin_amdgcn_ds_bpermute(paddr, __float_as_int(acct[3][m])));
            float lo = (lane & 32) ? p2 : p0;
            float hi = (lane & 32) ? p3 : p1;
            xr[m] = (lane & 16) ? hi : lo;
        }
        x0 = xr[0]; x1 = xr[1]; x2 = xr[2];
    }

    // ================== MAF flow: pk_fma hidden + even-packed outputs ==================
#pragma unroll
    for (int l = 0; l < 10; ++l) {
        const unsigned* L = ws + OFF_FL + l * 112;
        const half2_t* w0p = (const half2_t*)(L);
        const half2_t* w1p = (const half2_t*)(L + 16);
        const half2_t* bhp = (const half2_t*)(L + 32);
        const half2_t* m2w = (const half2_t*)(L + 48);
        const half2_t* a2w = (const half2_t*)(L + 64);
        const half2_t* m1w = (const half2_t*)(L + 80);
        const half2_t* a1w = (const half2_t*)(L + 88);
        const float*   sc  = (const float*)(L + 96);

        half2_t x0d = __builtin_amdgcn_cvt_pkrtz(x0, x0);
        half2_t x1d = __builtin_amdgcn_cvt_pkrtz(x1, x1);
        half2_t z = {0, 0};
        half2_t hp[16];
#pragma unroll
        for (int j = 0; j < 16; ++j) {
            half2_t h = __builtin_elementwise_fma(x1d, w1p[j], bhp[j]);
            h = __builtin_elementwise_fma(x0d, w0p[j], h);
            hp[j] = __builtin_elementwise_max(h, z);
        }

        float mu1 = sc[1], mu2 = sc[2], aa1 = sc[3], aa2 = sc[4];
#pragma unroll
        for (int kk = 0; kk < 16; ++kk) {
            mu2 = __builtin_amdgcn_fdot2(hp[kk], m2w[kk], mu2, false);
            aa2 = __builtin_amdgcn_fdot2(hp[kk], a2w[kk], aa2, false);
        }
#pragma unroll
        for (int p = 0; p < 8; ++p) {
            half2_t e = evens(hp[2 * p], hp[2 * p + 1]);
            mu1 = __builtin_amdgcn_fdot2(e, m1w[p], mu1, false);
            aa1 = __builtin_amdgcn_fdot2(e, a1w[p], aa1, false);
        }

        float t1 = fast_tanh(aa1);
        float t2 = fast_tanh(aa2);
        float y0 = (x0 - sc[0]) * sc[5];
        float y1 = (x1 - mu1) * __expf(-t1);
        float y2 = (x2 - mu2) * __expf(-t2);
        x0 = y2; x1 = y1; x2 = y0;
    }

    // ================== squash + HSV ==================
    float u0 = fast_rcp(1.0f + __expf(-x0));
    float u1 = fast_rcp(1.0f + __expf(-x1));
    float u2 = fast_rcp(1.0f + __expf(-x2));

    if (i < n) {
        out[3 * i + 0] = TWO_PI_F * u0;
        out[3 * i + 1] = u1;
        out[3 * i + 2] = u2;
    }
}

extern "C" void kernel_launch(void* const* d_in, const int* in_sizes, int n_in,
                              void* d_out, int out_size, void* d_ws, size_t ws_size,
                              hipStream_t stream) {
    const float* states = (const float*)d_in[0];
    const float* ew1  = (const float*)d_in[1];
    const float* eb1  = (const float*)d_in[2];
    const float* ew2  = (const float*)d_in[3];
    const float* eb2  = (const float*)d_in[4];
    const float* ew3  = (const float*)d_in[5];
    const float* eb3  = (const float*)d_in[6];
    const float* pw   = (const float*)d_in[7];
    const float* pb   = (const float*)d_in[8];
    const float* fwh  = (const float*)d_in[9];
    const float* fbh  = (const float*)d_in[10];
    const float* fwmu = (const float*)d_in[11];
    const float* fbmu = (const float*)d_in[12];
    const float* fwa  = (const float*)d_in[13];
    const float* fba  = (const float*)d_in[14];
    float* out = (float*)d_out;
    unsigned* ws = (unsigned*)d_ws;

    gsi_setup<<<1, 256, 0, stream>>>(ew1, ew2, ew3, eb3, pw, pb,
                                     fwh, fbh, fwmu, fbmu, fwa, fba, ws);

    int n = in_sizes[0] / 4;
    int grid = (n + 255) / 256;
    gsi_kernel<<<grid, 256, 0, stream>>>(states, eb1, eb2, ws, out, n);
}

// Round 8
// 97.973 us; speedup vs baseline: 2.7009x; 1.1300x over previous
//
#include <hip/hip_runtime.h>
#include <math.h>

#define TWO_PI_F 6.283185307179586f

typedef __fp16 half2_t __attribute__((ext_vector_type(2)));
typedef __fp16 half8_t __attribute__((ext_vector_type(8)));
typedef float  f32x4   __attribute__((ext_vector_type(4)));
typedef unsigned u32x2 __attribute__((ext_vector_type(2)));

// ---- d_ws layout (u32 units) ----
#define OFF_A1C   0      // [4 t][16 m15][2]  enc1 A compact
#define OFF_A2    128    // [4 (mt*2+kt)][64 lane][4 reg] enc2 A-frags
#define OFF_ATL   1152   // [64 lane][4 reg]  tail A-frag
#define OFF_ENCFB 1408   // [3] f32 folded tail bias (pad to 1424)
#define OFF_FL    1424   // [10][80] per-layer flow weights (SGPR-resident):
//   +0  w0e[8]  (fwh[0][4p], fwh[0][4p+2])
//   +8  w0o[8]  (fwh[0][4p+1], fwh[0][4p+3])
//   +16 w1o[8]  (fwh[1][4p+1], fwh[1][4p+3])
//   +24 m2e[8]  invc-scaled wmu[.][2] even
//   +32 m2o[8]  invc-scaled wmu[.][2] odd
//   +40 a2e[8]  wa[.][2] even
//   +48 a2o[8]  wa[.][2] odd
//   +56 m1[8]   wmu[even][1]
//   +64 a1[8]   wa[even][1]
//   +72 pad
#define OFF_FB    2224   // [10][24] per-layer LDS-staged block:
//   +0  bhe[8], +8 bho[8], +16 f32{B2fold, bmu1, ba2, ba1, LCe} +pad
#define OFF_FIN   2464   // 2 f32: {bm0_9, c0_9} final deferred affine
// total 2466 u32

__device__ __forceinline__ unsigned pack2(float a, float b) {
    half2_t h = __builtin_amdgcn_cvt_pkrtz(a, b);
    union { half2_t h; unsigned u; } cvt;
    cvt.h = h;
    return cvt.u;
}

__global__ __launch_bounds__(256)
void gsi_setup(const float* __restrict__ ew1, const float* __restrict__ ew2,
               const float* __restrict__ ew3, const float* __restrict__ eb3,
               const float* __restrict__ pw,  const float* __restrict__ pb,
               const float* __restrict__ fwh, const float* __restrict__ fbh,
               const float* __restrict__ fwmu, const float* __restrict__ fbmu,
               const float* __restrict__ fwa, const float* __restrict__ fba,
               unsigned* __restrict__ ws)
{
    int t = threadIdx.x;

    // enc1 A compact
    for (int idx = t; idx < 128; idx += 256) {
        int tt = idx >> 5, rest = idx & 31, m15 = rest >> 1, h = rest & 1;
        int f = 16 * tt + m15;
        ws[OFF_A1C + idx] = pack2(ew1[(2 * h) * 64 + f], ew1[(2 * h + 1) * 64 + f]);
    }
    // enc2 A-frags: c(q,j) = 32kt + 4q + (j&3) + 16*(j>>2)
    for (int idx = t; idx < 1024; idx += 256) {
        int r = idx & 3, l = (idx >> 2) & 63, f = idx >> 8;
        int mt = f >> 1, kt = f & 1, q = l >> 4, m = (l & 15) + 16 * mt;
        int j0 = 2 * r;
        int c0 = 32 * kt + 4 * q + (j0 & 3) + 16 * (j0 >> 2);
        ws[OFF_A2 + idx] = pack2(ew2[c0 * 32 + m], ew2[(c0 + 1) * 32 + m]);
    }
    // tail A-frag: Wf = ew3(32,8)@pw(8,3)
    for (int idx = t; idx < 256; idx += 256) {
        int lane = idx >> 2, r = idx & 3;
        int q = lane >> 4, m15 = lane & 15;
        unsigned v = 0;
        if (m15 < 3) {
            int j0 = 2 * r, j1 = 2 * r + 1;
            int k0 = 4 * q + (j0 & 3) + 16 * (j0 >> 2);
            int k1 = 4 * q + (j1 & 3) + 16 * (j1 >> 2);
            float w0 = 0.f, w1 = 0.f;
            for (int c = 0; c < 8; ++c) {
                w0 += ew3[k0 * 8 + c] * pw[c * 3 + m15];
                w1 += ew3[k1 * 8 + c] * pw[c * 3 + m15];
            }
            v = pack2(w0, w1);
        }
        ws[OFF_ATL + idx] = v;
    }
    if (t < 3) {
        float b = pb[t];
        for (int c = 0; c < 8; ++c) b += eb3[c] * pw[c * 3 + t];
        union { float f; unsigned u; } cvt; cvt.f = b;
        ws[OFF_ENCFB + t] = cvt.u;
    }

    // ---- flow weights (even/odd split; mu2 pre-scaled by 1/c0_{l-1}) ----
    for (int idx = t; idx < 80; idx += 256) {   // 10 layers x 8 p
        int l = idx >> 3, p = idx & 7;
        unsigned* L = ws + OFF_FL + l * 80;
        float invc = (l == 0) ? 1.0f : expf(tanhf(fba[(l - 1) * 3 + 0]));
        L[p]      = pack2(fwh[l * 96 + 4 * p],          fwh[l * 96 + 4 * p + 2]);
        L[8 + p]  = pack2(fwh[l * 96 + 4 * p + 1],      fwh[l * 96 + 4 * p + 3]);
        L[16 + p] = pack2(fwh[l * 96 + 32 + 4 * p + 1], fwh[l * 96 + 32 + 4 * p + 3]);
        L[24 + p] = pack2(fwmu[l * 96 + (4 * p) * 3 + 2] * invc,
                          fwmu[l * 96 + (4 * p + 2) * 3 + 2] * invc);
        L[32 + p] = pack2(fwmu[l * 96 + (4 * p + 1) * 3 + 2] * invc,
                          fwmu[l * 96 + (4 * p + 3) * 3 + 2] * invc);
        L[40 + p] = pack2(fwa[l * 96 + (4 * p) * 3 + 2],     fwa[l * 96 + (4 * p + 2) * 3 + 2]);
        L[48 + p] = pack2(fwa[l * 96 + (4 * p + 1) * 3 + 2], fwa[l * 96 + (4 * p + 3) * 3 + 2]);
        L[56 + p] = pack2(fwmu[l * 96 + (4 * p) * 3 + 1],    fwmu[l * 96 + (4 * p + 2) * 3 + 1]);
        L[64 + p] = pack2(fwa[l * 96 + (4 * p) * 3 + 1],     fwa[l * 96 + (4 * p + 2) * 3 + 1]);
    }
    // ---- LDS-staged per-layer block: biases + accumulator inits ----
    for (int idx = t; idx < 160; idx += 256) {  // 10 layers x 16 bias pairs
        int l = idx >> 4, j = idx & 15, p = j & 7;
        unsigned v = (j < 8) ? pack2(fbh[l * 32 + 4 * p],     fbh[l * 32 + 4 * p + 2])
                             : pack2(fbh[l * 32 + 4 * p + 1], fbh[l * 32 + 4 * p + 3]);
        ws[OFF_FB + l * 24 + j] = v;
    }
    if (t < 10) {
        int l = t;
        float c_prev  = (l == 0) ? 1.0f : expf(-tanhf(fba[(l - 1) * 3 + 0]));
        float bm0_prev = (l == 0) ? 0.0f : fbmu[(l - 1) * 3 + 0];
        float* F = (float*)(ws + OFF_FB + l * 24 + 16);
        F[0] = bm0_prev + fbmu[l * 3 + 2] / c_prev;   // B2fold
        F[1] = fbmu[l * 3 + 1];                        // bmu1
        F[2] = fba[l * 3 + 2];                         // ba2
        F[3] = fba[l * 3 + 1];                         // ba1
        F[4] = (l == 0) ? 0.0f : -tanhf(fba[(l - 1) * 3 + 0]);  // LCe = ln c0_{l-1}
    }
    if (t == 0) {
        float* F = (float*)(ws + OFF_FIN);
        F[0] = fbmu[9 * 3 + 0];
        F[1] = expf(-tanhf(fba[9 * 3 + 0]));
    }
}

__device__ __forceinline__ float fast_rcp(float x) { return __builtin_amdgcn_rcpf(x); }

__device__ __forceinline__ float fast_tanh(float x) {
    float ax = fabsf(x);
    float t = __expf(-2.0f * ax);
    float r = (1.0f - t) * fast_rcp(1.0f + t);
    return copysignf(r, x);
}

__device__ __forceinline__ unsigned relu2u(float a, float b) {
    half2_t p = __builtin_amdgcn_cvt_pkrtz(a, b);
    half2_t z = {0, 0};
    union { half2_t h; unsigned u; } cvt;
    cvt.h = __builtin_elementwise_max(p, z);
    return cvt.u;
}

__device__ __forceinline__ half8_t mk8(unsigned a, unsigned b, unsigned c, unsigned d) {
    union { unsigned u[4]; half8_t v; } r;
    r.u[0] = a; r.u[1] = b; r.u[2] = c; r.u[3] = d;
    return r.v;
}

__global__ __launch_bounds__(256)
void gsi_kernel(const float* __restrict__ states,
                const float* __restrict__ eb1, const float* __restrict__ eb2,
                const unsigned* __restrict__ ws,
                float* __restrict__ out, int n)
{
    __shared__ unsigned flds[240];
    if (threadIdx.x < 240) flds[threadIdx.x] = ws[OFF_FB + threadIdx.x];
    __syncthreads();

    int i = blockIdx.x * blockDim.x + threadIdx.x;
    int lane = threadIdx.x & 63;
    int wid = threadIdx.x >> 6;
    int rowbase = blockIdx.x * 256 + wid * 64;
    int q = lane >> 4;
    int l15 = lane & 15;
    bool q0 = (q == 0);

    const half8_t* a2p8  = (const half8_t*)(ws + OFF_A2);
    const float*   encfb = (const float*)(ws + OFF_ENCFB);

    // ---- persistent fragments ----
    half8_t aF1[4];
#pragma unroll
    for (int t = 0; t < 4; ++t) {
        u32x2 c = *(const u32x2*)(ws + OFF_A1C + t * 32 + l15 * 2);
        aF1[t] = mk8(q0 ? c.x : 0u, q0 ? c.y : 0u, 0u, 0u);
    }
    half8_t aF2[4];
#pragma unroll
    for (int f = 0; f < 4; ++f) aF2[f] = a2p8[f * 64 + lane];
    half8_t aFt = a2p8[4 * 64 + lane];

    f32x4 eb1c[4];
#pragma unroll
    for (int t = 0; t < 4; ++t) eb1c[t] = *(const f32x4*)(eb1 + 16 * t + 4 * q);
    f32x4 eb2c[2];
#pragma unroll
    for (int mt = 0; mt < 2; ++mt) eb2c[mt] = *(const f32x4*)(eb2 + 16 * mt + 4 * q);
    f32x4 tbias;
    {
        float e0 = encfb[0], e1 = encfb[1], e2 = encfb[2];
        tbias[0] = q0 ? e0 : 0.f;
        tbias[1] = q0 ? e1 : 0.f;
        tbias[2] = q0 ? e2 : 0.f;
        tbias[3] = 0.f;
    }

    // ================== encoder: all-MFMA, no LDS (verbatim R6/R7) ==================
    f32x4 acct[4];
#pragma unroll
    for (int nt = 0; nt < 4; ++nt) {
        int row = rowbase + 16 * nt + l15;
        row = row < n ? row : (n - 1);
        const float4 s = reinterpret_cast<const float4*>(states)[row];
        unsigned p01 = pack2(s.x, s.y);
        unsigned p23 = pack2(s.z, s.w);
        half8_t b1 = mk8(q0 ? p01 : 0u, q0 ? p23 : 0u, 0u, 0u);

        f32x4 acc1[4];
#pragma unroll
        for (int t = 0; t < 4; ++t)
            acc1[t] = __builtin_amdgcn_mfma_f32_16x16x32_f16(aF1[t], b1, eb1c[t], 0, 0, 0);

        half8_t b2f0 = mk8(relu2u(acc1[0][0], acc1[0][1]), relu2u(acc1[0][2], acc1[0][3]),
                           relu2u(acc1[1][0], acc1[1][1]), relu2u(acc1[1][2], acc1[1][3]));
        half8_t b2f1 = mk8(relu2u(acc1[2][0], acc1[2][1]), relu2u(acc1[2][2], acc1[2][3]),
                           relu2u(acc1[3][0], acc1[3][1]), relu2u(acc1[3][2], acc1[3][3]));

        f32x4 acc2[2];
#pragma unroll
        for (int mt = 0; mt < 2; ++mt) {
            f32x4 a = __builtin_amdgcn_mfma_f32_16x16x32_f16(aF2[mt * 2 + 0], b2f0, eb2c[mt], 0, 0, 0);
            acc2[mt] = __builtin_amdgcn_mfma_f32_16x16x32_f16(aF2[mt * 2 + 1], b2f1, a, 0, 0, 0);
        }

        half8_t btl = mk8(relu2u(acc2[0][0], acc2[0][1]), relu2u(acc2[0][2], acc2[0][3]),
                          relu2u(acc2[1][0], acc2[1][1]), relu2u(acc2[1][2], acc2[1][3]));

        acct[nt] = __builtin_amdgcn_mfma_f32_16x16x32_f16(aFt, btl, tbias, 0, 0, 0);
    }

    // redistribute x to owner lanes
    float x0, x1, x2;
    {
        int paddr = l15 * 4;
        float xr[3];
#pragma unroll
        for (int m = 0; m < 3; ++m) {
            float p0 = __int_as_float(__builtin_amdgcn_ds_bpermute(paddr, __float_as_int(acct[0][m])));
            float p1 = __int_as_float(__builtin_amdgcn_ds_bpermute(paddr, __float_as_int(acct[1][m])));
            float p2 = __int_as_float(__builtin_amdgcn_ds_bpermute(paddr, __float_as_int(acct[2][m])));
            float p3 = __int_as_float(__builtin_amdgcn_ds_bpermute(paddr, __float_as_int(acct[3][m])));
            float lo = (lane & 32) ? p2 : p0;
            float hi = (lane & 32) ? p3 : p1;
            xr[m] = (lane & 16) ? hi : lo;
        }
        x0 = xr[0]; x1 = xr[1]; x2 = xr[2];
    }

    // ================== MAF flow: even/odd split + LDS biases + y0-fold ==================
#pragma unroll
    for (int l = 0; l < 10; ++l) {
        const half2_t* w0e = (const half2_t*)(ws + OFF_FL + l * 80);
        const half2_t* w0o = (const half2_t*)(ws + OFF_FL + l * 80 + 8);
        const half2_t* w1o = (const half2_t*)(ws + OFF_FL + l * 80 + 16);
        const half2_t* m2e = (const half2_t*)(ws + OFF_FL + l * 80 + 24);
        const half2_t* m2o = (const half2_t*)(ws + OFF_FL + l * 80 + 32);
        const half2_t* a2e = (const half2_t*)(ws + OFF_FL + l * 80 + 40);
        const half2_t* a2o = (const half2_t*)(ws + OFF_FL + l * 80 + 48);
        const half2_t* m1w = (const half2_t*)(ws + OFF_FL + l * 80 + 56);
        const half2_t* a1w = (const half2_t*)(ws + OFF_FL + l * 80 + 64);

        const half2_t* bhe = (const half2_t*)(flds + l * 24);
        const half2_t* bho = (const half2_t*)(flds + l * 24 + 8);
        const float*   ini = (const float*)(flds + l * 24 + 16);

        half2_t x0d = __builtin_amdgcn_cvt_pkrtz(x0, x0);
        half2_t x1d = __builtin_amdgcn_cvt_pkrtz(x1, x1);
        half2_t z = {0, 0};

        half2_t he[8], ho[8];
#pragma unroll
        for (int p = 0; p < 8; ++p) {
            he[p] = __builtin_elementwise_max(
                        __builtin_elementwise_fma(x0d, w0e[p], bhe[p]), z);
            ho[p] = __builtin_elementwise_max(
                        __builtin_elementwise_fma(x0d, w0o[p],
                            __builtin_elementwise_fma(x1d, w1o[p], bho[p])), z);
        }

        float mu2 = ini[0], mu1 = ini[1], aa2 = ini[2], aa1 = ini[3];
#pragma unroll
        for (int p = 0; p < 8; ++p) {
            mu2 = __builtin_amdgcn_fdot2(he[p], m2e[p], mu2, false);
            mu2 = __builtin_amdgcn_fdot2(ho[p], m2o[p], mu2, false);
            aa2 = __builtin_amdgcn_fdot2(he[p], a2e[p], aa2, false);
            aa2 = __builtin_amdgcn_fdot2(ho[p], a2o[p], aa2, false);
            mu1 = __builtin_amdgcn_fdot2(he[p], m1w[p], mu1, false);
            aa1 = __builtin_amdgcn_fdot2(he[p], a1w[p], aa1, false);
        }

        float t1 = fast_tanh(aa1);
        float t2 = fast_tanh(aa2);
        float s2 = __expf(ini[4] - t2);   // c0_{l-1} * exp(-t2)
        float s1 = __expf(-t1);
        float y2 = (x2 - mu2) * s2;       // mu2 is the folded mu2' (pre-scaled weights)
        float y1 = (x1 - mu1) * s1;
        float nx2 = x0;                   // raw pass-through (affine deferred)
        x0 = y2; x1 = y1; x2 = nx2;
    }

    // pending layer-9 affine on the dim-0 slot (now in x2)
    {
        const float* fin = (const float*)(ws + OFF_FIN);
        x2 = (x2 - fin[0]) * fin[1];
    }

    // ================== squash + HSV ==================
    float u0 = fast_rcp(1.0f + __expf(-x0));
    float u1 = fast_rcp(1.0f + __expf(-x1));
    float u2 = fast_rcp(1.0f + __expf(-x2));

    if (i < n) {
        out[3 * i + 0] = TWO_PI_F * u0;
        out[3 * i + 1] = u1;
        out[3 * i + 2] = u2;
    }
}

extern "C" void kernel_launch(void* const* d_in, const int* in_sizes, int n_in,
                              void* d_out, int out_size, void* d_ws, size_t ws_size,
                              hipStream_t stream) {
    const float* states = (const float*)d_in[0];
    const float* ew1  = (const float*)d_in[1];
    const float* eb1  = (const float*)d_in[2];
    const float* ew2  = (const float*)d_in[3];
    const float* eb2  = (const float*)d_in[4];
    const float* ew3  = (const float*)d_in[5];
    const float* eb3  = (const float*)d_in[6];
    const float* pw   = (const float*)d_in[7];
    const float* pb   = (const float*)d_in[8];
    const float* fwh  = (const float*)d_in[9];
    const float* fbh  = (const float*)d_in[10];
    const float* fwmu = (const float*)d_in[11];
    const float* fbmu = (const float*)d_in[12];
    const float* fwa  = (const float*)d_in[13];
    const float* fba  = (const float*)d_in[14];
    float* out = (float*)d_out;
    unsigned* ws = (unsigned*)d_ws;

    gsi_setup<<<1, 256, 0, stream>>>(ew1, ew2, ew3, eb3, pw, pb,
                                     fwh, fbh, fwmu, fbmu, fwa, fba, ws);

    int n = in_sizes[0] / 4;
    int grid = (n + 255) / 256;
    gsi_kernel<<<grid, 256, 0, stream>>>(states, eb1, eb2, ws, out, n);
}